// Round 1
// baseline (820.040 us; speedup 1.0000x reference)
//
#include <hip/hip_runtime.h>
#include <stdint.h>

// YOLOv5 batched NMS. B=16 images, N=25200 boxes, NC=80 classes.
// Decomposition: class offsets (cls*4096) guarantee cross-class IoU == 0,
// so global greedy NMS == union of per-class greedy NMS, merged by
// (score desc, orig index asc) and truncated to 300.
//
// All comparison-feeding float math uses __f*_rn intrinsics to forbid FMA
// contraction -> bit-exact replication of the reference's IEEE f32 ops.

#define B      16
#define N      25200
#define NC     80
#define CAP    1024          // per-(img,class) bucket capacity (~235 expected, 50 sigma safe)
#define KSLOTS 16            // CAP / 64
#define MAXDET 300
#define CONF_T 0.25f
#define IOU_T  0.45f

typedef unsigned long long u64;
typedef unsigned int u32;

// monotone float -> u32 mapping (total order, handles the -1.0 sentinels)
__device__ __forceinline__ u32 fsort(float f) {
    u32 u = __float_as_uint(f);
    return u ^ ((u32)(((int)u) >> 31) | 0x80000000u);
}

// ---------------------------------------------------------------- preprocess
// One thread per box: conf/cls via strict-> argmax (first-occurrence ties),
// xywh->xyxy, validity, scatter valid indices into per-(img,class) buckets.
__global__ __launch_bounds__(256) void prep_kernel(
    const float* __restrict__ pred, float* __restrict__ conf,
    float4* __restrict__ box4, u32* __restrict__ bucket,
    int* __restrict__ cursor)
{
    int gid = blockIdx.x * 256 + threadIdx.x;
    if (gid >= B * N) return;
    int img = gid / N;
    int i   = gid - img * N;
    const float* x = pred + (size_t)gid * (5 + NC);
    float cx = x[0], cy = x[1], w = x[2], h = x[3], obj = x[4];
    float best = -1.0f; int bc = 0;
    #pragma unroll 8
    for (int c = 0; c < NC; ++c) {
        float t = __fmul_rn(x[5 + c], obj);     // cls_scores = x[:,5:] * obj
        if (t > best) { best = t; bc = c; }     // strict > == argmax first occurrence
    }
    float hw = __fmul_rn(w, 0.5f), hh = __fmul_rn(h, 0.5f);  // /2 exact
    float4 b;
    b.x = __fsub_rn(cx, hw); b.y = __fsub_rn(cy, hh);
    b.z = __fadd_rn(cx, hw); b.w = __fadd_rn(cy, hh);
    box4[gid] = b;
    conf[gid] = best;
    if (obj > CONF_T && best > CONF_T) {
        int slot = img * NC + bc;
        int pos = atomicAdd(&cursor[slot], 1);
        if (pos < CAP) bucket[(size_t)slot * CAP + pos] = (u32)i;
    }
}

// ---------------------------------------------------------------- per-class NMS
// One wave per (img, class). Offset boxes + scores live in registers
// (KSLOTS slots/lane, statically indexed via full unroll -> no scratch).
__global__ __launch_bounds__(64) void nms_kernel(
    const float* __restrict__ conf, const float4* __restrict__ box4,
    const u32* __restrict__ bucket, const int* __restrict__ cursor,
    u64* __restrict__ kept, int* __restrict__ keptCount)
{
    int bid  = blockIdx.x;                 // img*NC + cls
    int img  = bid / NC, cls = bid - img * NC;
    int lane = threadIdx.x;
    int n = cursor[bid]; if (n > CAP) n = CAP;
    int kmx = (n + 63) >> 6;               // live slot count
    float off = __fmul_rn((float)cls, 4096.0f);   // exact (int * 2^12)

    float sc[KSLOTS], x1[KSLOTS], y1[KSLOTS], x2[KSLOTS], y2[KSLOTS];
    u32 og[KSLOTS];
    #pragma unroll
    for (int k = 0; k < KSLOTS; ++k) {
        sc[k] = -1.0f; og[k] = 0xFFFFFFFFu;
        x1[k] = y1[k] = x2[k] = y2[k] = 0.0f;
        int idx = k * 64 + lane;
        if (idx < n) {
            u32 o = bucket[(size_t)bid * CAP + idx];
            og[k] = o;
            size_t g = (size_t)img * N + o;
            sc[k] = conf[g];
            float4 bb = box4[g];
            // boxes_off = box + cls*MAX_WH on all 4 coords, precomputed once
            // (same as reference precomputing boxes_off before the scan)
            x1[k] = __fadd_rn(bb.x, off);
            y1[k] = __fadd_rn(bb.y, off);
            x2[k] = __fadd_rn(bb.z, off);
            y2[k] = __fadd_rn(bb.w, off);
        }
    }

    u64 kbase = (u64)bid * MAXDET;
    int kc = 0;
    while (kc < MAXDET) {
        // ---- lane-local argmax: (score desc, orig asc)
        float bs = -1.0f; u32 bo = 0xFFFFFFFFu; int bslot = 0;
        #pragma unroll
        for (int k = 0; k < KSLOTS; ++k) {
            if (k < kmx) {
                if (sc[k] > bs || (sc[k] == bs && og[k] < bo)) {
                    bs = sc[k]; bo = og[k]; bslot = k;
                }
            }
        }
        u32 skey = fsort(bs);
        u64 key = ((u64)skey << 32) | (u64)(~bo);   // max key = max score, tie -> min orig
        #pragma unroll
        for (int d = 32; d; d >>= 1) {
            u64 k2 = __shfl_xor(key, d, 64);
            if (k2 > key) key = k2;
        }
        if ((u32)(key >> 32) <= 0x80000000u) break;  // no live score > 0

        // winner lane (unique: orig indices are unique)
        bool iwin = (skey == (u32)(key >> 32)) && ((u32)(~bo) == (u32)key);
        u64 wm = __ballot(iwin);
        int wl = __ffsll(wm) - 1;
        int wslot = __shfl(bslot, wl, 64);

        // broadcast selected offset-box (static select chain, then shuffle)
        float sx1 = x1[0], sy1 = y1[0], sx2 = x2[0], sy2 = y2[0];
        #pragma unroll
        for (int k = 1; k < KSLOTS; ++k) {
            if (wslot == k) { sx1 = x1[k]; sy1 = y1[k]; sx2 = x2[k]; sy2 = y2[k]; }
        }
        sx1 = __shfl(sx1, wl, 64); sy1 = __shfl(sy1, wl, 64);
        sx2 = __shfl(sx2, wl, 64); sy2 = __shfl(sy2, wl, 64);
        float wconf = __shfl(bs, wl, 64);
        u32 worig = ~(u32)key;

        if (lane == 0) {
            // merge key: score bits (positive -> monotone) | (0x7FFF-orig) | cls
            kept[kbase + kc] = ((u64)__float_as_uint(wconf) << 32)
                             | ((u64)(0x7FFFu - worig) << 16) | (u64)cls;
        }
        kc++;

        // explicit self-kill (reference: live.at[idx].set(-1); guards NaN IoU)
        if (lane == wl) {
            #pragma unroll
            for (int k = 0; k < KSLOTS; ++k) if (k == wslot) sc[k] = -1.0f;
        }

        // IoU suppression, op-for-op with the reference
        float sarea = __fmul_rn(__fsub_rn(sx2, sx1), __fsub_rn(sy2, sy1));
        #pragma unroll
        for (int k = 0; k < KSLOTS; ++k) {
            if (k < kmx && sc[k] > 0.0f) {
                float ltx = fmaxf(sx1, x1[k]);
                float lty = fmaxf(sy1, y1[k]);
                float rbx = fminf(sx2, x2[k]);
                float rby = fminf(sy2, y2[k]);
                float wx  = fmaxf(__fsub_rn(rbx, ltx), 0.0f);
                float wy  = fmaxf(__fsub_rn(rby, lty), 0.0f);
                float inter = __fmul_rn(wx, wy);
                float a2 = __fmul_rn(__fsub_rn(x2[k], x1[k]), __fsub_rn(y2[k], y1[k]));
                float denom = __fsub_rn(__fadd_rn(sarea, a2), inter);
                float iou = __fdiv_rn(inter, denom);   // 0/0 -> NaN -> compare false
                if (iou > IOU_T) sc[k] = -1.0f;
            }
        }
    }
    if (lane == 0) keptCount[bid] = kc;
}

// ---------------------------------------------------------------- merge
// One block (2 waves) per image: 80-way merge of sorted kept lists, 300 rows.
__global__ __launch_bounds__(128) void merge_kernel(
    const float4* __restrict__ box4, const u64* __restrict__ kept,
    const int* __restrict__ keptCount, float* __restrict__ out)
{
    int img = blockIdx.x;
    int t = threadIdx.x;
    __shared__ u64 wk[2];
    int cnt = 0, h = 0;
    const u64* list = kept + (size_t)(img * NC + (t < NC ? t : 0)) * MAXDET;
    u64 head = 0;
    if (t < NC) {
        cnt = keptCount[img * NC + t];
        if (cnt > 0) head = list[0];
    }
    float* dets  = out + (size_t)img * MAXDET * 6;
    float* keeps = out + (size_t)B * MAXDET * 6 + (size_t)img * MAXDET;

    for (int r = 0; r < MAXDET; ++r) {
        u64 k = head;
        #pragma unroll
        for (int d = 32; d; d >>= 1) {
            u64 k2 = __shfl_xor(k, d, 64);
            if (k2 > k) k = k2;
        }
        if ((t & 63) == 0) wk[t >> 6] = k;
        __syncthreads();
        u64 kmaxv = wk[0] > wk[1] ? wk[0] : wk[1];
        __syncthreads();                    // wk reused next iteration
        if (kmaxv == 0ULL) {
            // exhausted: zero-fill remaining rows (matches dets*keeps==0)
            for (int rr = r + t; rr < MAXDET; rr += 128) {
                #pragma unroll
                for (int j = 0; j < 6; ++j) dets[rr * 6 + j] = 0.0f;
                keeps[rr] = 0.0f;
            }
            return;
        }
        if (head == kmaxv) {                // unique winner (orig unique)
            u32 lo = (u32)kmaxv;
            int cls  = (int)(lo & 0xFFFFu);
            int orig = 0x7FFF - (int)((lo >> 16) & 0x7FFFu);
            float cf = __uint_as_float((u32)(kmaxv >> 32));
            float4 b = box4[(size_t)img * N + orig];
            dets[r * 6 + 0] = b.x; dets[r * 6 + 1] = b.y;
            dets[r * 6 + 2] = b.z; dets[r * 6 + 3] = b.w;
            dets[r * 6 + 4] = cf;  dets[r * 6 + 5] = (float)cls;
            keeps[r] = 1.0f;
            h++;
            head = (h < cnt) ? list[h] : 0ULL;
        }
    }
}

// ---------------------------------------------------------------- launch
extern "C" void kernel_launch(void* const* d_in, const int* in_sizes, int n_in,
                              void* d_out, int out_size, void* d_ws, size_t ws_size,
                              hipStream_t stream)
{
    const float* pred = (const float*)d_in[0];
    float* out = (float*)d_out;
    char* ws = (char*)d_ws;

    // workspace layout (16.4 MB total)
    int*    cursor    = (int*)ws;                                  //  5120 B
    int*    keptCount = (int*)(ws + 5120);                         //  5120 B
    u32*    bucket    = (u32*)(ws + 10240);                        //  5,242,880 B
    float*  conf      = (float*)(ws + 10240 + (size_t)B * NC * CAP * 4);
    float4* box4      = (float4*)((char*)conf + (size_t)B * N * 4);   // 16B aligned
    u64*    kept      = (u64*)((char*)box4 + (size_t)B * N * 16);

    hipMemsetAsync(d_ws, 0, 10240, stream);   // zero cursors + keptCount
    prep_kernel<<<(B * N + 255) / 256, 256, 0, stream>>>(pred, conf, box4, bucket, cursor);
    nms_kernel<<<B * NC, 64, 0, stream>>>(conf, box4, bucket, cursor, kept, keptCount);
    merge_kernel<<<B, 128, 0, stream>>>(box4, kept, keptCount, out);
}

// Round 2
// 369.153 us; speedup vs baseline: 2.2214x; 2.2214x over previous
//
#include <hip/hip_runtime.h>
#include <stdint.h>

// YOLOv5 batched NMS. B=16 images, N=25200 boxes, NC=80 classes.
// Per-class decomposition (cls*4096 offsets => cross-class IoU == 0).
// NMS = rank-ordered mask scan: rank via key-count, suppressor masks via
// parallel IoU, in-block greedy via ballot loop. Merge = histogram select
// + bitonic sort of the kept-key union (selection order provably == key desc).
//
// All comparison-feeding float math uses __f*_rn intrinsics (no FMA
// contraction) -> bit-exact replication of the reference's IEEE f32 ops.
// IEEE rn add/mul/min/max are commutative -> pairwise IoU predicate is
// symmetric and may be precomputed per unordered pair.

#define B      16
#define N      25200
#define NC     80
#define CAP    384          // per-(img,class) capacity: mean 235, sd 15 -> 9.7 sigma
#define NSLOT  6            // CAP / 64
#define MAXDET 300
#define CONF_T 0.25f
#define IOU_T  0.45f

typedef unsigned long long u64;
typedef unsigned int u32;

__device__ __forceinline__ bool iou_gt(const float4 a, float aArea, const float4 b) {
    // op-for-op with reference _iou_one_vs_all (commutative ops -> symmetric)
    float ltx = fmaxf(a.x, b.x), lty = fmaxf(a.y, b.y);
    float rbx = fminf(a.z, b.z), rby = fminf(a.w, b.w);
    float wx = fmaxf(__fsub_rn(rbx, ltx), 0.0f);
    float wy = fmaxf(__fsub_rn(rby, lty), 0.0f);
    float inter = __fmul_rn(wx, wy);
    float bArea = __fmul_rn(__fsub_rn(b.z, b.x), __fsub_rn(b.w, b.y));
    float denom = __fsub_rn(__fadd_rn(aArea, bArea), inter);
    return __fdiv_rn(inter, denom) > IOU_T;    // 0/0 -> NaN -> false (matches ref)
}

// ---------------------------------------------------------------- preprocess
__global__ __launch_bounds__(256) void prep_kernel(
    const float* __restrict__ pred, float4* __restrict__ box4,
    u64* __restrict__ bucket, int* __restrict__ cursor)
{
    int gid = blockIdx.x * 256 + threadIdx.x;
    if (gid >= B * N) return;
    int img = gid / N;
    int i   = gid - img * N;
    const float* x = pred + (size_t)gid * (5 + NC);
    float cx = x[0], cy = x[1], w = x[2], h = x[3], obj = x[4];
    float best = -1.0f; int bc = 0;
    #pragma unroll 8
    for (int c = 0; c < NC; ++c) {
        float t = __fmul_rn(x[5 + c], obj);     // cls_scores = x[:,5:] * obj
        if (t > best) { best = t; bc = c; }     // strict > == argmax first index
    }
    float hw = __fmul_rn(w, 0.5f), hh = __fmul_rn(h, 0.5f);
    float4 b;
    b.x = __fsub_rn(cx, hw); b.y = __fsub_rn(cy, hh);
    b.z = __fadd_rn(cx, hw); b.w = __fadd_rn(cy, hh);
    box4[gid] = b;
    if (obj > CONF_T && best > CONF_T) {
        int slot = img * NC + bc;
        int pos = atomicAdd(&cursor[slot], 1);
        if (pos < CAP)
            // key: conf bits (conf>0 -> monotone as u32) | ~orig (asc orig wins ties)
            bucket[(size_t)slot * CAP + pos] =
                ((u64)__float_as_uint(best) << 32) | (u64)(u32)(~(u32)i);
    }
}

// ---------------------------------------------------------------- per-class NMS
// One wave per (img,class). Rank -> scatter -> per-64-block mask scan.
__global__ __launch_bounds__(64) void nms_kernel(
    const float4* __restrict__ box4, const u64* __restrict__ bucket,
    const int* __restrict__ cursor, u64* __restrict__ kept,
    int* __restrict__ keptCount)
{
    int bid  = blockIdx.x;                 // img*NC + cls
    int img  = bid / NC, cls = bid - img * NC;
    int lane = threadIdx.x;
    int n = cursor[bid]; if (n > CAP) n = CAP;

    __shared__ u64    keyL[CAP];           // bucket-order, then rank-order after scatter
    __shared__ float4 bxR[CAP];            // offset boxes, rank-order

    float off = __fmul_rn((float)cls, 4096.0f);   // exact

    // ---- phase A: load, offset coords, keys
    u64 key[NSLOT]; float4 bx[NSLOT];
    #pragma unroll
    for (int s = 0; s < NSLOT; ++s) {
        int idx = s * 64 + lane;
        key[s] = 0;
        if (idx < n) {
            u64 k = bucket[(size_t)bid * CAP + idx];
            key[s] = k;
            u32 orig = ~((u32)k);
            float4 b = box4[(size_t)img * N + orig];
            float4 c;
            c.x = __fadd_rn(b.x, off); c.y = __fadd_rn(b.y, off);
            c.z = __fadd_rn(b.z, off); c.w = __fadd_rn(b.w, off);
            bx[s] = c;
            keyL[idx] = k;
        }
    }
    __syncthreads();

    // ---- phase B: rank by counting (keys unique -> permutation)
    int rank[NSLOT];
    #pragma unroll
    for (int s = 0; s < NSLOT; ++s) rank[s] = 0;
    #pragma unroll 4
    for (int j = 0; j < n; ++j) {
        u64 kj = keyL[j];                   // LDS broadcast
        #pragma unroll
        for (int s = 0; s < NSLOT; ++s) rank[s] += (kj > key[s]) ? 1 : 0;
    }
    __syncthreads();

    // ---- phase C: scatter by rank (keyL alias safe: keys held in regs)
    #pragma unroll
    for (int s = 0; s < NSLOT; ++s) {
        int idx = s * 64 + lane;
        if (idx < n) { keyL[rank[s]] = key[s]; bxR[rank[s]] = bx[s]; }
    }
    __syncthreads();

    // ---- phase D: greedy scan over 64-rank blocks
    u64 kw0 = 0, kw1 = 0, kw2 = 0, kw3 = 0, kw4 = 0, kw5 = 0;
    int cnt = 0;
    int bmax = (n + 63) >> 6;
    u64 base = (u64)bid * CAP;
    for (int b = 0; b < bmax; ++b) {
        int r = b * 64 + lane;
        bool valid = r < n;
        float4 me = bxR[r];                 // r < CAP always; garbage if !valid (harmless)
        u64 mykey = keyL[r];
        float ma = __fmul_rn(__fsub_rn(me.z, me.x), __fsub_rn(me.w, me.y));

        // dead vs prior kept blocks (iterate kept bits only)
        bool dead = false;
        #pragma unroll
        for (int w = 0; w < NSLOT; ++w) {
            if (w < b) {
                u64 m = (w == 0) ? kw0 : (w == 1) ? kw1 : (w == 2) ? kw2
                      : (w == 3) ? kw3 : (w == 4) ? kw4 : kw5;
                while (m) {
                    int j = __ffsll((long long)m) - 1; m &= m - 1;
                    float4 o4 = bxR[w * 64 + j];        // uniform broadcast
                    dead = dead || iou_gt(me, ma, o4);
                }
            }
        }

        // own-block suppressor mask (bit j: rank b*64+j suppresses me)
        u64 mysup = 0;
        #pragma unroll 4
        for (int j = 0; j < 64; ++j) {
            float4 o4 = bxR[b * 64 + j];
            bool bit = ((b * 64 + j) < n) && iou_gt(me, ma, o4);
            mysup |= ((u64)bit) << j;
        }

        // in-block greedy via ballot loop (serial part: ~kept_in_block iters)
        u64 aliveM = __ballot(valid && !dead);
        u64 dec = ~aliveM;
        u64 kb = 0;
        while (dec != ~0ull) {
            int wbit = __ffsll((long long)~dec) - 1;    // lowest undecided = kept
            kb |= 1ull << wbit;
            u64 killed = __ballot((mysup >> wbit) & 1);
            dec |= killed | (1ull << wbit);             // explicit self-kill (NaN guard)
        }

        if (b == 0) kw0 = kb; else if (b == 1) kw1 = kb; else if (b == 2) kw2 = kb;
        else if (b == 3) kw3 = kb; else if (b == 4) kw4 = kb; else kw5 = kb;

        // emit kept merge-keys in rank order
        if (valid && ((kb >> lane) & 1)) {
            int pos = cnt + __popcll(kb & ((1ull << lane) - 1));
            u32 cbits = (u32)(mykey >> 32);
            u32 orig  = ~((u32)mykey);
            kept[base + pos] = ((u64)cbits << 32)
                             | ((u64)(0x7FFFu - orig) << 16) | (u64)cls;
        }
        cnt += __popcll(kb);
    }
    if (lane == 0) keptCount[bid] = cnt;
}

// ---------------------------------------------------------------- merge
// One block per image: exact top-300 of the kept-key union via histogram
// threshold + bitonic sort. (Global selection order == key descending.)
__global__ __launch_bounds__(256) void merge_kernel(
    const float4* __restrict__ box4, const u64* __restrict__ kept,
    const int* __restrict__ keptCount, float* __restrict__ out)
{
    int img = blockIdx.x;
    int tid = threadIdx.x;
    __shared__ u32 hist[4096];
    __shared__ u64 sel[1024];
    __shared__ u32 part[256];
    __shared__ int cnts[NC];
    __shared__ int sB, sHi, sSel;

    for (int i = tid; i < 4096; i += 256) hist[i] = 0;
    if (tid < NC) cnts[tid] = keptCount[img * NC + tid];
    if (tid == 0) { sB = -1; sHi = 0; sSel = 0; }
    __syncthreads();

    // pass 1: histogram of floor(conf*4096) (monotone in key)
    for (int c = 0; c < NC; ++c) {
        int cn = cnts[c];
        const u64* lst = kept + (size_t)(img * NC + c) * CAP;
        for (int i = tid; i < cn; i += 256) {
            u64 k = lst[i];
            float cf = __uint_as_float((u32)(k >> 32));
            int q = (int)__fmul_rn(cf, 4096.0f);
            if (q > 4095) q = 4095;
            atomicAdd(&hist[q], 1u);
        }
    }
    __syncthreads();

    // suffix scan over 256 chunks of 16 bins
    u32 pt = 0;
    #pragma unroll
    for (int k2 = 0; k2 < 16; ++k2) pt += hist[tid * 16 + k2];
    part[tid] = pt;
    __syncthreads();
    u32 S = pt;
    for (int offn = 1; offn < 256; offn <<= 1) {
        u32 v = (tid + offn < 256) ? part[tid + offn] : 0;
        __syncthreads();
        S += v; part[tid] = S;
        __syncthreads();
    }
    // crossing thread locates threshold bin B: suffix(B) >= 300 > suffix(B+1)
    u32 Snext = S - pt;
    if (S >= MAXDET && Snext < MAXDET) {
        u32 run = Snext;
        for (int k2 = 15; k2 >= 0; --k2) {
            u32 hgt = hist[tid * 16 + k2];
            run += hgt;
            if (run >= MAXDET) { sB = tid * 16 + k2; sHi = (int)(run - hgt); break; }
        }
    }
    __syncthreads();
    int Bq = sB;                            // -1 => total < 300 => take all

    // pass 2: collect keys with q >= B  (count = sHi + hist[B] <= 299 + hist[B])
    for (int c = 0; c < NC; ++c) {
        int cn = cnts[c];
        const u64* lst = kept + (size_t)(img * NC + c) * CAP;
        for (int i = tid; i < cn; i += 256) {
            u64 k = lst[i];
            float cf = __uint_as_float((u32)(k >> 32));
            int q = (int)__fmul_rn(cf, 4096.0f);
            if (q > 4095) q = 4095;
            if (q >= Bq) {
                int p = atomicAdd(&sSel, 1);
                if (p < 1024) sel[p] = k;
            }
        }
    }
    __syncthreads();
    int selCnt = sSel; if (selCnt > 1024) selCnt = 1024;
    for (int i = selCnt + tid; i < 1024; i += 256) sel[i] = 0;
    __syncthreads();

    // bitonic sort descending, 1024 elems
    for (int k2 = 2; k2 <= 1024; k2 <<= 1) {
        for (int j2 = k2 >> 1; j2 > 0; j2 >>= 1) {
            for (int i = tid; i < 1024; i += 256) {
                int ix = i ^ j2;
                if (ix > i) {
                    u64 a = sel[i], bb = sel[ix];
                    bool up = ((i & k2) == 0);
                    if (up ? (a < bb) : (a > bb)) { sel[i] = bb; sel[ix] = a; }
                }
            }
            __syncthreads();
        }
    }

    // emit
    int outCnt = selCnt < MAXDET ? selCnt : MAXDET;
    float* dets  = out + (size_t)img * MAXDET * 6;
    float* keeps = out + (size_t)B * MAXDET * 6 + (size_t)img * MAXDET;
    for (int r = tid; r < MAXDET; r += 256) {
        if (r < outCnt) {
            u64 k = sel[r];
            float cf = __uint_as_float((u32)(k >> 32));
            int orig = 0x7FFF - (int)((k >> 16) & 0x7FFF);
            int cl   = (int)(k & 0xFFFF);
            float4 b = box4[(size_t)img * N + orig];
            dets[r * 6 + 0] = b.x; dets[r * 6 + 1] = b.y;
            dets[r * 6 + 2] = b.z; dets[r * 6 + 3] = b.w;
            dets[r * 6 + 4] = cf;  dets[r * 6 + 5] = (float)cl;
            keeps[r] = 1.0f;
        } else {
            #pragma unroll
            for (int j = 0; j < 6; ++j) dets[r * 6 + j] = 0.0f;
            keeps[r] = 0.0f;
        }
    }
}

// ---------------------------------------------------------------- launch
extern "C" void kernel_launch(void* const* d_in, const int* in_sizes, int n_in,
                              void* d_out, int out_size, void* d_ws, size_t ws_size,
                              hipStream_t stream)
{
    const float* pred = (const float*)d_in[0];
    float* out = (float*)d_out;
    char* ws = (char*)d_ws;

    // workspace layout (~14.3 MB)
    int*    cursor    = (int*)ws;                                   // 5120 B
    u64*    bucket    = (u64*)(ws + 5120);                          // 1280*384*8
    float4* box4      = (float4*)(ws + 5120 + (size_t)B * NC * CAP * 8);   // 16B aligned
    u64*    kept      = (u64*)((char*)box4 + (size_t)B * N * 16);
    int*    keptCount = (int*)((char*)kept + (size_t)B * NC * CAP * 8);

    hipMemsetAsync(d_ws, 0, 5120, stream);   // zero cursors
    prep_kernel<<<(B * N + 255) / 256, 256, 0, stream>>>(pred, box4, bucket, cursor);
    nms_kernel<<<B * NC, 64, 0, stream>>>(box4, bucket, cursor, kept, keptCount);
    merge_kernel<<<B, 256, 0, stream>>>(box4, kept, keptCount, out);
}